// Round 2
// baseline (47.239 us; speedup 1.0000x reference)
//
#include <hip/hip_runtime.h>
#include <math.h>

// LocalGroupedZernikeNewBP: fused grouped soft-abs + 3x3 box gain + tanh.
// Layout [B=8, H=256, W=256, C=36] fp32, channel-last.
// Groups: special 0..2 (plain tanh), low 3..5, mid 6..14, high 15..35.
//
// R2: all global traffic coalesced via LDS round-trip.
//  - stage 18x18 halo-inclusive raw tile into LDS (linear float4 copy)
//  - per-pixel group sums read from LDS (stride-144B b128: aggregate
//    conflict-free, 8 lane-groups on disjoint bank quads)
//  - box sum via padded LDS sum arrays; outputs written back over dead
//    raw slots; coalesced LDS->global store.

static constexpr int IMG = 256;
static constexpr int NB = 8;
static constexpr int C = 36;
static constexpr int TS = 16;          // interior tile
static constexpr int HT = TS + 2;      // halo-inclusive (18)
static constexpr int ROWF4 = HT * 9;   // float4 per halo row = 162
static constexpr int NSTAGE4 = HT * HT * 9;  // 2916 float4 staged
static constexpr int NOUT4 = TS * TS * 9;    // 2304 float4 out

__device__ __forceinline__ float fast_tanh(float x) {
    // tanh(x) = 1 - 2/(exp(2x)+1); saturates correctly at +-inf
    float e = __expf(2.0f * x);
    return 1.0f - __fdividef(2.0f, e + 1.0f);
}

__device__ __forceinline__ void group_sums(const float* __restrict__ v,
                                           float b_lo, float e_lo,
                                           float b_mi, float e_mi,
                                           float b_hi, float e_hi,
                                           float& tlo, float& tmi, float& thi) {
    float lo = 0.f, mi = 0.f, hi = 0.f;
    #pragma unroll
    for (int c = 3; c < 6; ++c)   { float u = v[c] + b_lo; lo += sqrtf(u * u + e_lo); }
    #pragma unroll
    for (int c = 6; c < 15; ++c)  { float u = v[c] + b_mi; mi += sqrtf(u * u + e_mi); }
    #pragma unroll
    for (int c = 15; c < 36; ++c) { float u = v[c] + b_hi; hi += sqrtf(u * u + e_hi); }
    tlo = lo; tmi = mi; thi = hi;
}

__global__ __launch_bounds__(256) void lgz_kernel(
    const float* __restrict__ in, float* __restrict__ out,
    const float* __restrict__ p_sp_bias, const float* __restrict__ p_sp_alpha,
    const float* __restrict__ p_sp_amax,
    const float* __restrict__ p_lo_bias, const float* __restrict__ p_lo_alpha,
    const float* __restrict__ p_lo_amax, const float* __restrict__ p_lo_eps,
    const float* __restrict__ p_lo_gss, const float* __restrict__ p_lo_psat,
    const float* __restrict__ p_mi_bias, const float* __restrict__ p_mi_alpha,
    const float* __restrict__ p_mi_amax, const float* __restrict__ p_mi_eps,
    const float* __restrict__ p_mi_gss, const float* __restrict__ p_mi_psat,
    const float* __restrict__ p_hi_bias, const float* __restrict__ p_hi_alpha,
    const float* __restrict__ p_hi_amax, const float* __restrict__ p_hi_eps,
    const float* __restrict__ p_hi_gss, const float* __restrict__ p_hi_psat)
{
    __shared__ __align__(16) float s_raw[HT * HT * C];   // 46656 B
    __shared__ float s_sum[3][HT][HT + 1];               // 4104 B (padded rows)

    const int tid = threadIdx.x;
    const int tx = tid & 15, ty = tid >> 4;
    const int bx0 = blockIdx.x * TS, by0 = blockIdx.y * TS;
    const int b = blockIdx.z;

    const float b_sp = p_sp_bias[0], a_sp = p_sp_alpha[0], m_sp = p_sp_amax[0];
    const float b_lo = p_lo_bias[0], a_lo = p_lo_alpha[0], m_lo = p_lo_amax[0];
    const float e_lo = p_lo_eps[0],  g_lo = p_lo_gss[0],  q_lo = p_lo_psat[0];
    const float b_mi = p_mi_bias[0], a_mi = p_mi_alpha[0], m_mi = p_mi_amax[0];
    const float e_mi = p_mi_eps[0],  g_mi = p_mi_gss[0],  q_mi = p_mi_psat[0];
    const float b_hi = p_hi_bias[0], a_hi = p_hi_alpha[0], m_hi = p_hi_amax[0];
    const float e_hi = p_hi_eps[0],  g_hi = p_hi_gss[0],  q_hi = p_hi_psat[0];

    const float* img = in + (size_t)b * IMG * IMG * C;
    float* outimg = out + (size_t)b * IMG * IMG * C;

    // ---- phase 0: coalesced stage of 18x18 halo-inclusive raw tile ----
    #pragma unroll
    for (int it = 0; it < (NSTAGE4 + 255) / 256; ++it) {
        int F4 = tid + it * 256;
        if (F4 < NSTAGE4) {
            int r = F4 / ROWF4;
            int rem = F4 - r * ROWF4;
            int px = rem / 9;
            int j = rem - px * 9;
            int gy = min(max(by0 + r - 1, 0), IMG - 1);
            int gx = min(max(bx0 + px - 1, 0), IMG - 1);
            float4 val = *reinterpret_cast<const float4*>(
                img + ((size_t)gy * IMG + gx) * C + j * 4);
            *reinterpret_cast<float4*>(s_raw + (r * HT + px) * C + j * 4) = val;
        }
    }
    __syncthreads();

    // ---- phase 1: per-pixel group sums ----
    float v[C];  // own interior pixel stays in registers
    {
        const float* src = s_raw + ((ty + 1) * HT + (tx + 1)) * C;
        #pragma unroll
        for (int j = 0; j < 9; ++j)
            reinterpret_cast<float4*>(v)[j] = reinterpret_cast<const float4*>(src)[j];
    }
    {
        float tlo, tmi, thi;
        group_sums(v, b_lo, e_lo, b_mi, e_mi, b_hi, e_hi, tlo, tmi, thi);
        s_sum[0][ty + 1][tx + 1] = tlo;
        s_sum[1][ty + 1][tx + 1] = tmi;
        s_sum[2][ty + 1][tx + 1] = thi;
    }
    // halo ring: 2*18 + 2*16 = 68 pixels, first 68 threads
    if (tid < 68) {
        int hy, hx;
        if (tid < 18)      { hy = 0;            hx = tid; }
        else if (tid < 36) { hy = HT - 1;       hx = tid - 18; }
        else if (tid < 52) { hy = tid - 36 + 1; hx = 0; }
        else               { hy = tid - 52 + 1; hx = HT - 1; }
        float w[C];
        const float* src = s_raw + (hy * HT + hx) * C;
        #pragma unroll
        for (int j = 0; j < 9; ++j)
            reinterpret_cast<float4*>(w)[j] = reinterpret_cast<const float4*>(src)[j];
        float tlo, tmi, thi;
        group_sums(w, b_lo, e_lo, b_mi, e_mi, b_hi, e_hi, tlo, tmi, thi);
        s_sum[0][hy][hx] = tlo;
        s_sum[1][hy][hx] = tmi;
        s_sum[2][hy][hx] = thi;
    }
    __syncthreads();

    // ---- phase 2: 3x3 box sums, gains, outputs (in-register), writeback ----
    float slo = 0.f, smi = 0.f, shi = 0.f;
    #pragma unroll
    for (int di = 0; di < 3; ++di) {
        #pragma unroll
        for (int dj = 0; dj < 3; ++dj) {
            slo += s_sum[0][ty + di][tx + dj];
            smi += s_sum[1][ty + di][tx + dj];
            shi += s_sum[2][ty + di][tx + dj];
        }
    }
    const float glo = a_lo * __fdividef(g_lo, 1.0f + __fdividef(slo, q_lo));
    const float gmi = a_mi * __fdividef(g_mi, 1.0f + __fdividef(smi, q_mi));
    const float ghi = a_hi * __fdividef(g_hi, 1.0f + __fdividef(shi, q_hi));

    #pragma unroll
    for (int c = 0; c < 3; ++c)   v[c] = m_sp * fast_tanh(a_sp * (v[c] + b_sp));
    #pragma unroll
    for (int c = 3; c < 6; ++c)   v[c] = m_lo * fast_tanh(glo * (v[c] + b_lo));
    #pragma unroll
    for (int c = 6; c < 15; ++c)  v[c] = m_mi * fast_tanh(gmi * (v[c] + b_mi));
    #pragma unroll
    for (int c = 15; c < 36; ++c) v[c] = m_hi * fast_tanh(ghi * (v[c] + b_hi));

    {   // overwrite own (now dead) raw slot with outputs
        float* dst = s_raw + ((ty + 1) * HT + (tx + 1)) * C;
        #pragma unroll
        for (int j = 0; j < 9; ++j)
            reinterpret_cast<float4*>(dst)[j] = reinterpret_cast<const float4*>(v)[j];
    }
    __syncthreads();

    // ---- phase 3: coalesced store of interior ----
    #pragma unroll
    for (int it = 0; it < NOUT4 / 256; ++it) {  // exactly 9
        int F4 = tid + it * 256;
        int p = F4 / 9;
        int j = F4 - p * 9;
        int r = p >> 4, cc = p & 15;
        float4 val = *reinterpret_cast<const float4*>(
            s_raw + ((r + 1) * HT + (cc + 1)) * C + 4 * j);
        *reinterpret_cast<float4*>(
            outimg + ((size_t)(by0 + r) * IMG + (bx0 + cc)) * C + 4 * j) = val;
    }
}

extern "C" void kernel_launch(void* const* d_in, const int* in_sizes, int n_in,
                              void* d_out, int out_size, void* d_ws, size_t ws_size,
                              hipStream_t stream) {
    const float* raw = (const float*)d_in[0];
    dim3 grid(IMG / TS, IMG / TS, NB);
    dim3 block(256);
    lgz_kernel<<<grid, block, 0, stream>>>(
        raw, (float*)d_out,
        (const float*)d_in[1], (const float*)d_in[2], (const float*)d_in[3],
        (const float*)d_in[5], (const float*)d_in[6], (const float*)d_in[7],
        (const float*)d_in[8], (const float*)d_in[9], (const float*)d_in[10],
        (const float*)d_in[11], (const float*)d_in[12], (const float*)d_in[13],
        (const float*)d_in[14], (const float*)d_in[15], (const float*)d_in[16],
        (const float*)d_in[17], (const float*)d_in[18], (const float*)d_in[19],
        (const float*)d_in[20], (const float*)d_in[21], (const float*)d_in[22]);
}